// Round 6
// baseline (847.876 us; speedup 1.0000x reference)
//
#include <hip/hip_runtime.h>
#include <hip/hip_bf16.h>
#include <stdint.h>

// ---------------------------------------------------------------------------
// AttendedSeqEmbedding: ragged bidirectional GRU + MLP + attention pooling
// I=128, H=64, O=128, B=512, T<=512
//   K0 offsets   : prefix-sum of seqlens
//   K1 prep      : f32 -> bf16 hi/lo weight splits, fused gate biases
//   K2 gemm_gx   : gx[tok][384] = x @ [Wih_f;Wih_b]^T + biases (MFMA hi/lo)
//   K3 scan      : 1024 scans batched 16-wide as MFMA N-dim, h in LDS dbuf.
//                  gx staged via global_load_lds DMA, double-buffered 4-step
//                  chunks; one counted vmcnt(12) per chunk; lgkm-only step
//                  barriers so DMAs stay in flight (T3/T4 pattern).
//   K4 gemm_mlp  : mlp[tok][128] = tanh(hs @ Wm^T + bm), scores = mlp . ctx
//   K5 pool      : per-seq softmax(scores) weighted sum, 4 t-slices/block
// ---------------------------------------------------------------------------

typedef __attribute__((ext_vector_type(8))) short short8;
typedef __attribute__((ext_vector_type(4))) float f32x4;

__device__ __forceinline__ unsigned short f2bf(float f) {
  unsigned int u = __float_as_uint(f);
  u = (u + 0x7FFFu + ((u >> 16) & 1u)) >> 16;
  return (unsigned short)u;
}
__device__ __forceinline__ float bf2f(unsigned short h) {
  return __uint_as_float(((unsigned int)h) << 16);
}
__device__ __forceinline__ void f2bf2(float f, unsigned short& hi, unsigned short& lo) {
  hi = f2bf(f);
  lo = f2bf(f - bf2f(hi));
}
__device__ __forceinline__ f32x4 mfma16(short8 a, short8 b, f32x4 c) {
  return __builtin_amdgcn_mfma_f32_16x16x32_bf16(a, b, c, 0, 0, 0);
}
__device__ __forceinline__ float rcpf(float x) { return __builtin_amdgcn_rcpf(x); }
__device__ __forceinline__ float sigm(float x) { return rcpf(1.f + __expf(-x)); }
__device__ __forceinline__ float tanhft(float x) {
  float e = __expf(2.f * x);
  return 1.f - 2.f * rcpf(e + 1.f);
}

// async global->LDS DMA, 16B per lane; LDS dest = uniform base + lane*16.
#define GLDS(SRC, DST)                                        \
  __builtin_amdgcn_global_load_lds(                           \
      (const __attribute__((address_space(1))) void*)(SRC),   \
      (__attribute__((address_space(3))) void*)(DST), 16, 0, 0)

// ---------------------------------------------------------------- K0: offsets
__global__ void k_offsets(const int* __restrict__ seqlens, int* __restrict__ off) {
  __shared__ int s[512];
  int t = threadIdx.x;
  s[t] = seqlens[t];
  __syncthreads();
  for (int d = 1; d < 512; d <<= 1) {
    int v = (t >= d) ? s[t - d] : 0;
    __syncthreads();
    s[t] += v;
    __syncthreads();
  }
  if (t == 0) off[0] = 0;
  off[t + 1] = s[t];
}

// ------------------------------------------------------------------- K1: prep
__global__ void k_prep(const float* __restrict__ Wih_f, const float* __restrict__ Wih_b,
                       const float* __restrict__ bih_f, const float* __restrict__ bhh_f,
                       const float* __restrict__ bih_b, const float* __restrict__ bhh_b,
                       const float* __restrict__ Wm,
                       unsigned short* __restrict__ Wcat_hi, unsigned short* __restrict__ Wcat_lo,
                       float* __restrict__ biasA,
                       unsigned short* __restrict__ Wm_hi, unsigned short* __restrict__ Wm_lo) {
  int idx = blockIdx.x * 256 + threadIdx.x;
  int stride = gridDim.x * 256;
  for (int i = idx; i < 384 * 128; i += stride) {
    int r = i >> 7, c = i & 127;
    float v = (r < 192) ? Wih_f[r * 128 + c] : Wih_b[(r - 192) * 128 + c];
    unsigned short hi, lo;
    f2bf2(v, hi, lo);
    Wcat_hi[i] = hi;
    Wcat_lo[i] = lo;
  }
  for (int i = idx; i < 128 * 128; i += stride) {
    unsigned short hi, lo;
    f2bf2(Wm[i], hi, lo);
    Wm_hi[i] = hi;
    Wm_lo[i] = lo;
  }
  for (int i = idx; i < 384; i += stride) {
    int d = i / 192, j = i % 192;
    const float* bi = d ? bih_b : bih_f;
    const float* bh = d ? bhh_b : bhh_f;
    biasA[i] = bi[j] + ((j < 128) ? bh[j] : 0.f);
  }
}

// ---------------------------------------------------------------- K2: gx GEMM
__global__ __launch_bounds__(256) void k_gemm_gx(
    const float* __restrict__ x, const unsigned short* __restrict__ Bhi,
    const unsigned short* __restrict__ Blo, const float* __restrict__ biasA,
    float* __restrict__ gx, int total) {
  __shared__ unsigned short Ahi[64][136];
  __shared__ unsigned short Alo[64][136];
  const int tid = threadIdx.x;
  const int base = blockIdx.x * 64;
  {
    int row = tid & 63, cc = tid >> 6;
    int grow = base + row;
    if (grow >= total) grow = total - 1;
    const float* src = x + (size_t)grow * 128 + cc * 32;
#pragma unroll
    for (int u = 0; u < 8; ++u) {
      f32x4 v = *(const f32x4*)(src + u * 4);
#pragma unroll
      for (int e = 0; e < 4; ++e) {
        unsigned short h_, l_;
        f2bf2(v[e], h_, l_);
        Ahi[row][cc * 32 + u * 4 + e] = h_;
        Alo[row][cc * 32 + u * 4 + e] = l_;
      }
    }
  }
  __syncthreads();
  const int w = tid >> 6, l = tid & 63;
  const int lr = l & 15, lg = l >> 4;
  short8 afh[4], afl[4];
#pragma unroll
  for (int kc = 0; kc < 4; ++kc) {
    afh[kc] = *(const short8*)&Ahi[w * 16 + lr][kc * 32 + lg * 8];
    afl[kc] = *(const short8*)&Alo[w * 16 + lr][kc * 32 + lg * 8];
  }
#pragma unroll 1
  for (int nt = 0; nt < 24; ++nt) {
    const int ncol = nt * 16 + lr;
    const float bias = biasA[ncol];
    f32x4 acc = {bias, bias, bias, bias};
#pragma unroll
    for (int kc = 0; kc < 4; ++kc) {
      short8 bh = *(const short8*)(Bhi + (size_t)ncol * 128 + kc * 32 + lg * 8);
      short8 bl = *(const short8*)(Blo + (size_t)ncol * 128 + kc * 32 + lg * 8);
      acc = mfma16(afh[kc], bh, acc);
      acc = mfma16(afl[kc], bh, acc);
      acc = mfma16(afh[kc], bl, acc);
    }
#pragma unroll
    for (int q = 0; q < 4; ++q) {
      int row = base + w * 16 + lg * 4 + q;
      if (row < total) gx[(size_t)row * 384 + ncol] = acc[q];
    }
  }
}

// ------------------------------------------------------------------- K3: scan
// 64 wgs: wg = (seqblock<<1)|dir ; 16 seqs per wg as MFMA N-dim.
// 4 waves: wave w owns output rows j in [16w,16w+16) for all 3 gates.
// gx staged in LDS: gxl[buf][step4][colquad48][seq16][4f]. Per chunk each
// wave issues 12 DMAs (3/step); each thread's global src = its own seq row,
// cols (w*3+ii)*16 + lg*4. Read back: 3x ds_read_b128 per step, 2-way banks.
// vmcnt(12): the 12 newest vmem ops are the next chunk's DMAs; anything the
// compiler adds only makes this over-wait (fail-safe), never stale.
__global__ __launch_bounds__(256, 1) void k_scan(
    const float* __restrict__ gx, const int* __restrict__ off,
    const int* __restrict__ seqlens, const float* __restrict__ Whh_f,
    const float* __restrict__ Whh_b, const float* __restrict__ bhh_f,
    const float* __restrict__ bhh_b, float* __restrict__ hs) {
  __shared__ float gxl[2][4][3072];                  // 96 KB
  __shared__ unsigned short hbuf[2][2][2][16][40];   // 20 KB
  const int wg = blockIdx.x;
  const int dir = wg & 1;
  const int sblk = wg >> 1;
  const int tid = threadIdx.x;
  const int w = tid >> 6, l = tid & 63;
  const int b16 = l & 15, lg = l >> 4;
  const int seq = sblk * 16 + b16;
  const int len = seqlens[seq];
  const int start = off[seq];
  const float* Whh = dir ? Whh_b : Whh_f;
  const float* bhh = dir ? bhh_b : bhh_f;
  const int dirbase = dir * 192;
  const int j0 = w * 16 + lg * 4;

  // A-fragments of Whh (hi/lo), 3 gates x 2 k-chunks
  short8 Ah[3][2], Al[3][2];
#pragma unroll
  for (int g = 0; g < 3; ++g) {
#pragma unroll
    for (int kc = 0; kc < 2; ++kc) {
      const float* wp = Whh + (size_t)(g * 64 + w * 16 + b16) * 64 + kc * 32 + lg * 8;
      f32x4 v0 = *(const f32x4*)wp;
      f32x4 v1 = *(const f32x4*)(wp + 4);
      short8 hh, ll;
#pragma unroll
      for (int e = 0; e < 4; ++e) {
        unsigned short h_, l_;
        f2bf2(v0[e], h_, l_);
        hh[e] = (short)h_;
        ll[e] = (short)l_;
      }
#pragma unroll
      for (int e = 0; e < 4; ++e) {
        unsigned short h_, l_;
        f2bf2(v1[e], h_, l_);
        hh[4 + e] = (short)h_;
        ll[4 + e] = (short)l_;
      }
      Ah[g][kc] = hh;
      Al[g][kc] = ll;
    }
  }
  const f32x4 bhhN = *(const f32x4*)(bhh + 128 + j0);

  int ml = len;
#pragma unroll
  for (int m = 1; m < 16; m <<= 1) ml = max(ml, __shfl_xor(ml, m, 64));
  const int ml4 = (ml + 3) & ~3;

  // zero h buffer 0
  const int kcW = w >> 1;
  const int koffW = (w & 1) * 16 + lg * 4;
  {
    uint2 z2;
    z2.x = 0u; z2.y = 0u;
    *(uint2*)&hbuf[0][0][kcW][b16][koffW] = z2;
    *(uint2*)&hbuf[0][1][kcW][b16][koffW] = z2;
  }
  f32x4 h = {0.f, 0.f, 0.f, 0.f};

  // walking pointers (clamped to last valid row)
  const int p0 = dir ? (len - 1) : 0;
  const float* pp = gx + (size_t)(start + p0) * 384 + dirbase + lg * 4;  // prefetch
  float* hp = hs + (size_t)(start + p0) * 128 + dir * 64 + j0;           // hs out
  const ptrdiff_t gstep = dir ? -384 : 384;
  const ptrdiff_t hstep = dir ? -128 : 128;
  const int wcol = w * 48;  // + ii*16 per issue

  // issue chunk 0 (steps 0..3) into buffer 0
  int tp = 0;  // next step to prefetch
#pragma unroll
  for (int sc = 0; sc < 4; ++sc) {
    GLDS(pp + wcol, &gxl[0][sc][(w * 3 + 0) * 256]);
    GLDS(pp + wcol + 16, &gxl[0][sc][(w * 3 + 1) * 256]);
    GLDS(pp + wcol + 32, &gxl[0][sc][(w * 3 + 2) * 256]);
    if (tp + 1 < len) pp += gstep;
    ++tp;
  }

#define SCAN_STEP(SC)                                                          \
  {                                                                            \
    const int s = t0 + (SC);                                                   \
    const float* gbase = &gxl[bf][SC][(w * 4 + lg) * 64 + b16 * 4];            \
    f32x4 gxr = *(const f32x4*)gbase;                                          \
    f32x4 gxz = *(const f32x4*)(gbase + 1024);                                 \
    f32x4 gxn = *(const f32x4*)(gbase + 2048);                                 \
    short8 bhf0 = *(const short8*)&hbuf[(SC) & 1][0][0][b16][lg * 8];          \
    short8 bhf1 = *(const short8*)&hbuf[(SC) & 1][0][1][b16][lg * 8];          \
    short8 blf0 = *(const short8*)&hbuf[(SC) & 1][1][0][b16][lg * 8];          \
    short8 blf1 = *(const short8*)&hbuf[(SC) & 1][1][1][b16][lg * 8];          \
    f32x4 ara = gxr, aza = gxz, ana = bhhN;                                    \
    f32x4 zz = {0.f, 0.f, 0.f, 0.f};                                           \
    f32x4 arb = zz, azb = zz, anb = zz;                                        \
    ara = mfma16(Ah[0][0], bhf0, ara);                                         \
    aza = mfma16(Ah[1][0], bhf0, aza);                                         \
    ana = mfma16(Ah[2][0], bhf0, ana);                                         \
    arb = mfma16(Ah[0][1], bhf1, arb);                                         \
    azb = mfma16(Ah[1][1], bhf1, azb);                                         \
    anb = mfma16(Ah[2][1], bhf1, anb);                                         \
    ara = mfma16(Ah[0][0], blf0, ara);                                         \
    aza = mfma16(Ah[1][0], blf0, aza);                                         \
    ana = mfma16(Ah[2][0], blf0, ana);                                         \
    arb = mfma16(Ah[0][1], blf1, arb);                                         \
    azb = mfma16(Ah[1][1], blf1, azb);                                         \
    anb = mfma16(Ah[2][1], blf1, anb);                                         \
    ara = mfma16(Al[0][0], bhf0, ara);                                         \
    aza = mfma16(Al[1][0], bhf0, aza);                                         \
    ana = mfma16(Al[2][0], bhf0, ana);                                         \
    arb = mfma16(Al[0][1], bhf1, arb);                                         \
    azb = mfma16(Al[1][1], bhf1, azb);                                         \
    anb = mfma16(Al[2][1], bhf1, anb);                                         \
    f32x4 ar = ara + arb, az = aza + azb, an = ana + anb;                      \
    f32x4 hn;                                                                  \
    _Pragma("unroll") for (int q = 0; q < 4; ++q) {                            \
      float r = sigm(ar[q]);                                                   \
      float z = sigm(az[q]);                                                   \
      float n = tanhft(gxn[q] + r * an[q]);                                    \
      hn[q] = z * (h[q] - n) + n;                                              \
    }                                                                          \
    const bool valid = (s < len);                                              \
    _Pragma("unroll") for (int q = 0; q < 4; ++q) h[q] = valid ? hn[q] : h[q]; \
    *(f32x4*)hp = h; /* frozen-h makes the padded-step store idempotent */     \
    if (s + 1 < len) hp += hstep;                                              \
    unsigned int b0 = __float_as_uint(h[0]);                                   \
    unsigned int b1 = __float_as_uint(h[1]);                                   \
    unsigned int b2 = __float_as_uint(h[2]);                                   \
    unsigned int b3 = __float_as_uint(h[3]);                                   \
    uint2 whi;                                                                 \
    whi.x = (b0 >> 16) | (b1 & 0xFFFF0000u);                                   \
    whi.y = (b2 >> 16) | (b3 & 0xFFFF0000u);                                   \
    float l0 = h[0] - __uint_as_float(b0 & 0xFFFF0000u);                       \
    float l1 = h[1] - __uint_as_float(b1 & 0xFFFF0000u);                       \
    float l2 = h[2] - __uint_as_float(b2 & 0xFFFF0000u);                       \
    float l3 = h[3] - __uint_as_float(b3 & 0xFFFF0000u);                       \
    uint2 wlo;                                                                 \
    wlo.x = (__float_as_uint(l0) >> 16) | (__float_as_uint(l1) & 0xFFFF0000u); \
    wlo.y = (__float_as_uint(l2) >> 16) | (__float_as_uint(l3) & 0xFFFF0000u); \
    *(uint2*)&hbuf[((SC) + 1) & 1][0][kcW][b16][koffW] = whi;                  \
    *(uint2*)&hbuf[((SC) + 1) & 1][1][kcW][b16][koffW] = wlo;                  \
    asm volatile("s_waitcnt lgkmcnt(0)" ::: "memory");                         \
    __builtin_amdgcn_s_barrier();                                              \
    __builtin_amdgcn_sched_barrier(0);                                         \
  }

#pragma unroll 1
  for (int t0 = 0; t0 < ml4; t0 += 4) {
    const int bf = (t0 >> 2) & 1;
    const int bfn = bf ^ 1;
    // (A) issue next chunk's DMAs into the other buffer
    __builtin_amdgcn_sched_barrier(0);
#pragma unroll
    for (int sc = 0; sc < 4; ++sc) {
      GLDS(pp + wcol, &gxl[bfn][sc][(w * 3 + 0) * 256]);
      GLDS(pp + wcol + 16, &gxl[bfn][sc][(w * 3 + 1) * 256]);
      GLDS(pp + wcol + 32, &gxl[bfn][sc][(w * 3 + 2) * 256]);
      if (tp + 1 < len) pp += gstep;
      ++tp;
    }
    // (B) wait for current chunk's DMAs (12 newest in flight are next chunk's)
    __builtin_amdgcn_sched_barrier(0);
    asm volatile("s_waitcnt vmcnt(12) lgkmcnt(0)" ::: "memory");
    // (C) all waves' DMAs for this chunk have landed
    __builtin_amdgcn_s_barrier();
    __builtin_amdgcn_sched_barrier(0);
    SCAN_STEP(0)
    SCAN_STEP(1)
    SCAN_STEP(2)
    SCAN_STEP(3)
  }
#undef SCAN_STEP
  // never end the program with LDS-DMA outstanding
  asm volatile("s_waitcnt vmcnt(0)" ::: "memory");
}

// --------------------------------------------------------------- K4: MLP GEMM
__global__ __launch_bounds__(256) void k_gemm_mlp(
    const float* __restrict__ hs, const unsigned short* __restrict__ Bhi,
    const unsigned short* __restrict__ Blo, const float* __restrict__ bm,
    const float* __restrict__ ctx, float* __restrict__ mlp,
    float* __restrict__ scores, int total) {
  __shared__ unsigned short Ahi[64][136];
  __shared__ unsigned short Alo[64][136];
  const int tid = threadIdx.x;
  const int base = blockIdx.x * 64;
  {
    int row = tid & 63, cc = tid >> 6;
    int grow = base + row;
    if (grow >= total) grow = total - 1;
    const float* src = hs + (size_t)grow * 128 + cc * 32;
#pragma unroll
    for (int u = 0; u < 8; ++u) {
      f32x4 v = *(const f32x4*)(src + u * 4);
#pragma unroll
      for (int e = 0; e < 4; ++e) {
        unsigned short h_, l_;
        f2bf2(v[e], h_, l_);
        Ahi[row][cc * 32 + u * 4 + e] = h_;
        Alo[row][cc * 32 + u * 4 + e] = l_;
      }
    }
  }
  __syncthreads();
  const int w = tid >> 6, l = tid & 63;
  const int lr = l & 15, lg = l >> 4;
  short8 afh[4], afl[4];
#pragma unroll
  for (int kc = 0; kc < 4; ++kc) {
    afh[kc] = *(const short8*)&Ahi[w * 16 + lr][kc * 32 + lg * 8];
    afl[kc] = *(const short8*)&Alo[w * 16 + lr][kc * 32 + lg * 8];
  }
  float sc0 = 0.f, sc1 = 0.f, sc2 = 0.f, sc3 = 0.f;
#pragma unroll 1
  for (int nt = 0; nt < 8; ++nt) {
    const int ncol = nt * 16 + lr;
    const float bias = bm[ncol];
    const float cv = ctx[ncol];
    f32x4 acc = {bias, bias, bias, bias};
#pragma unroll
    for (int kc = 0; kc < 4; ++kc) {
      short8 bh = *(const short8*)(Bhi + (size_t)ncol * 128 + kc * 32 + lg * 8);
      short8 bl = *(const short8*)(Blo + (size_t)ncol * 128 + kc * 32 + lg * 8);
      acc = mfma16(afh[kc], bh, acc);
      acc = mfma16(afl[kc], bh, acc);
      acc = mfma16(afh[kc], bl, acc);
    }
    const int r0 = base + w * 16 + lg * 4;
    float tv0 = tanhft(acc[0]);
    float tv1 = tanhft(acc[1]);
    float tv2 = tanhft(acc[2]);
    float tv3 = tanhft(acc[3]);
    if (r0 + 0 < total) mlp[(size_t)(r0 + 0) * 128 + ncol] = tv0;
    if (r0 + 1 < total) mlp[(size_t)(r0 + 1) * 128 + ncol] = tv1;
    if (r0 + 2 < total) mlp[(size_t)(r0 + 2) * 128 + ncol] = tv2;
    if (r0 + 3 < total) mlp[(size_t)(r0 + 3) * 128 + ncol] = tv3;
    sc0 += tv0 * cv;
    sc1 += tv1 * cv;
    sc2 += tv2 * cv;
    sc3 += tv3 * cv;
  }
#pragma unroll
  for (int m = 1; m < 16; m <<= 1) {
    sc0 += __shfl_xor(sc0, m, 64);
    sc1 += __shfl_xor(sc1, m, 64);
    sc2 += __shfl_xor(sc2, m, 64);
    sc3 += __shfl_xor(sc3, m, 64);
  }
  if (lr == 0) {
    const int r0 = base + w * 16 + lg * 4;
    if (r0 + 0 < total) scores[r0 + 0] = sc0;
    if (r0 + 1 < total) scores[r0 + 1] = sc1;
    if (r0 + 2 < total) scores[r0 + 2] = sc2;
    if (r0 + 3 < total) scores[r0 + 3] = sc3;
  }
}

// ------------------------------------------------------------------- K5: pool
__global__ __launch_bounds__(512) void k_pool(
    const float* __restrict__ scores, const float* __restrict__ mlp,
    const int* __restrict__ off, const int* __restrict__ seqlens,
    float* __restrict__ out) {
  const int s = blockIdx.x;
  const int tid = threadIdx.x;
  const int len = seqlens[s];
  const int st = off[s];
  const int col = tid & 127, slice = tid >> 7;
  float m = (tid < len) ? scores[st + tid] : -1e30f;
#pragma unroll
  for (int d = 1; d < 64; d <<= 1) m = fmaxf(m, __shfl_xor(m, d, 64));
  __shared__ float wmx[8];
  if ((tid & 63) == 0) wmx[tid >> 6] = m;
  __syncthreads();
  m = wmx[0];
#pragma unroll
  for (int i = 1; i < 8; ++i) m = fmaxf(m, wmx[i]);
  float acc = 0.f, ws = 0.f;
  for (int t = slice; t < len; t += 4) {
    float wv = __expf(scores[st + t] - m);
    ws += wv;
    acc += wv * mlp[(size_t)(st + t) * 128 + col];
  }
  __shared__ float accs[4][128];
  __shared__ float wss[4];
  accs[slice][col] = acc;
  if (col == 0) wss[slice] = ws;
  __syncthreads();
  if (tid < 128) {
    float a = accs[0][tid] + accs[1][tid] + accs[2][tid] + accs[3][tid];
    float wsum = wss[0] + wss[1] + wss[2] + wss[3];
    out[(size_t)s * 128 + tid] = a * rcpf(wsum);
  }
}

// ---------------------------------------------------------------------- launch
extern "C" void kernel_launch(void* const* d_in, const int* in_sizes, int n_in,
                              void* d_out, int out_size, void* d_ws, size_t ws_size,
                              hipStream_t stream) {
  const float* seqs = (const float*)d_in[0];
  const int* seqlens = (const int*)d_in[1];
  const float* Wih_f = (const float*)d_in[2];
  const float* Whh_f = (const float*)d_in[3];
  const float* bih_f = (const float*)d_in[4];
  const float* bhh_f = (const float*)d_in[5];
  const float* Wih_b = (const float*)d_in[6];
  const float* Whh_b = (const float*)d_in[7];
  const float* bih_b = (const float*)d_in[8];
  const float* bhh_b = (const float*)d_in[9];
  const float* Wm = (const float*)d_in[10];
  const float* bm = (const float*)d_in[11];
  const float* ctx = (const float*)d_in[12];

  const int total = in_sizes[0] / 128;

  char* ws = (char*)d_ws;
  size_t o = 0;
  auto alloc = [&](size_t bytes) {
    size_t r = o;
    o = (o + bytes + 255) & ~(size_t)255;
    return r;
  };
  int* off = (int*)(ws + alloc(513 * 4));
  unsigned short* Wcat_hi = (unsigned short*)(ws + alloc(384 * 128 * 2));
  unsigned short* Wcat_lo = (unsigned short*)(ws + alloc(384 * 128 * 2));
  float* biasA = (float*)(ws + alloc(384 * 4));
  unsigned short* Wm_hi = (unsigned short*)(ws + alloc(128 * 128 * 2));
  unsigned short* Wm_lo = (unsigned short*)(ws + alloc(128 * 128 * 2));
  float* scores = (float*)(ws + alloc((size_t)total * 4));
  float* gxbuf = (float*)(ws + alloc((size_t)total * 384 * 4));
  float* hsbuf = (float*)(ws + alloc((size_t)total * 128 * 4));
  float* mlp = gxbuf;  // reuse gx region after the scan

  k_offsets<<<1, 512, 0, stream>>>(seqlens, off);
  k_prep<<<64, 256, 0, stream>>>(Wih_f, Wih_b, bih_f, bhh_f, bih_b, bhh_b, Wm,
                                 Wcat_hi, Wcat_lo, biasA, Wm_hi, Wm_lo);
  const int mt = (total + 63) / 64;
  k_gemm_gx<<<mt, 256, 0, stream>>>(seqs, Wcat_hi, Wcat_lo, biasA, gxbuf, total);
  k_scan<<<64, 256, 0, stream>>>(gxbuf, off, seqlens, Whh_f, Whh_b, bhh_f, bhh_b, hsbuf);
  k_gemm_mlp<<<mt, 256, 0, stream>>>(hsbuf, Wm_hi, Wm_lo, bm, ctx, mlp, scores, total);
  k_pool<<<512, 512, 0, stream>>>(scores, mlp, off, seqlens, (float*)d_out);
}